// Round 14
// baseline (194.159 us; speedup 1.0000x reference)
//
#include <hip/hip_runtime.h>
#include <math.h>

typedef __bf16 bf16_t;
typedef __bf16 v8bf __attribute__((ext_vector_type(8)));
typedef __bf16 v4bf __attribute__((ext_vector_type(4)));
typedef float  v4f  __attribute__((ext_vector_type(4)));

#define AS1 __attribute__((address_space(1)))
#define AS3 __attribute__((address_space(3)))

// async global->LDS 16B copy; LDS dest = wave-uniform base + lane*16
static __device__ __forceinline__ void load_lds16(const bf16_t* g, bf16_t* l) {
    __builtin_amdgcn_global_load_lds((AS1 void*)const_cast<bf16_t*>(g),
                                     (AS3 void*)l, 16, 0, 0);
}

// sin/cos via native HW ops with explicit revolution reduction (no libcall)
static __device__ __forceinline__ void fast_sincos(float ang, float* sn, float* cs) {
    float rv = ang * 0.15915494309189535f;
    rv -= floorf(rv);
    const float a = rv * 6.283185307179586f;
    *sn = __sinf(a);
    *cs = __cosf(a);
}

// ---------------------------------------------------------------------------
// Kernel 0: fp32 -> bf16 for wo only (h/wq/wk/wv conversion fused into qkv).
// 1M elems, 8/thread, 512 blocks.
// ---------------------------------------------------------------------------
__global__ __launch_bounds__(256) void cvt_wo(
    const float* __restrict__ wo, bf16_t* __restrict__ wob)
{
    const size_t i8 = ((size_t)blockIdx.x * 256 + threadIdx.x) * 8;
    const float4 a = *(const float4*)(wo + i8);
    const float4 b = *(const float4*)(wo + i8 + 4);
    v8bf o;
    o[0]=(bf16_t)a.x; o[1]=(bf16_t)a.y; o[2]=(bf16_t)a.z; o[3]=(bf16_t)a.w;
    o[4]=(bf16_t)b.x; o[5]=(bf16_t)b.y; o[6]=(bf16_t)b.z; o[7]=(bf16_t)b.w;
    *(v8bf*)(wob + i8) = o;
}

// ---------------------------------------------------------------------------
// Kernel 1: QKV = h @ [wq|wk|wv]^T, fused RoPE on Q,K. Inputs fp32; the
// fp32->bf16 conversion happens during LDS staging (float4 loads + packed
// cvt + ds_write_b128 — r3-verified code). Q,K: [32][2048][64];
// V TRANSPOSED: [32][64][2048]. Epilogue stores wave-coalesced v8bf via LDS.
// ---------------------------------------------------------------------------
__global__ __launch_bounds__(256) void qkv_gemm_rope(
    const float* __restrict__ A,    // h fp32 [4096][1024]
    const float* __restrict__ wq,
    const float* __restrict__ wk,
    const float* __restrict__ wv,
    bf16_t* __restrict__ qo, bf16_t* __restrict__ ko, bf16_t* __restrict__ vo)
{
    __shared__ __align__(16) bf16_t smem[17408];
    bf16_t* As = smem;
    bf16_t* Bs = smem + 4096;

    const int tid = threadIdx.x;
    const int n0  = blockIdx.x * 128;
    const int m0  = blockIdx.y * 128;
    const int sel = n0 >> 10;               // 0=Q 1=K 2=V
    const float* W = (sel == 0) ? wq : (sel == 1) ? wk : wv;
    const int wr0 = n0 & 1023;

    const int wave = tid >> 6;
    const int lane = tid & 63;
    const int l16  = lane & 15;
    const int quad = lane >> 4;
    const int wrow = (wave >> 1) * 64;
    const int wcol = (wave & 1) * 64;

    v4f acc[4][4];
    #pragma unroll
    for (int i = 0; i < 4; ++i)
        #pragma unroll
        for (int j = 0; j < 4; ++j) acc[i][j] = (v4f)(0.0f);

    for (int kt = 0; kt < 32; ++kt) {
        const int k0 = kt * 32;
        #pragma unroll
        for (int rep = 0; rep < 2; ++rep) {
            const int c   = rep * 256 + tid;     // chunk 0..511
            const int row = c >> 2;              // 0..127
            const int col = (c & 3) * 8;         // 0,8,16,24
            const float* pa = A + (size_t)(m0 + row) * 1024 + k0 + col;
            const float* pb = W + (size_t)(wr0 + row) * 1024 + k0 + col;
            const float4 a0 = *(const float4*)pa;
            const float4 a1 = *(const float4*)(pa + 4);
            const float4 b0 = *(const float4*)pb;
            const float4 b1 = *(const float4*)(pb + 4);
            v8bf av, bv;
            av[0] = (bf16_t)a0.x; av[1] = (bf16_t)a0.y; av[2] = (bf16_t)a0.z; av[3] = (bf16_t)a0.w;
            av[4] = (bf16_t)a1.x; av[5] = (bf16_t)a1.y; av[6] = (bf16_t)a1.z; av[7] = (bf16_t)a1.w;
            bv[0] = (bf16_t)b0.x; bv[1] = (bf16_t)b0.y; bv[2] = (bf16_t)b0.z; bv[3] = (bf16_t)b0.w;
            bv[4] = (bf16_t)b1.x; bv[5] = (bf16_t)b1.y; bv[6] = (bf16_t)b1.z; bv[7] = (bf16_t)b1.w;
            *(v8bf*)&As[c * 8] = av;
            *(v8bf*)&Bs[c * 8] = bv;
        }
        __syncthreads();

        v8bf af[4], bfb[4];
        #pragma unroll
        for (int i = 0; i < 4; ++i) {
            af[i]  = *(const v8bf*)&As[(wrow + i * 16 + l16) * 32 + quad * 8];
            bfb[i] = *(const v8bf*)&Bs[(wcol + i * 16 + l16) * 32 + quad * 8];
        }
        #pragma unroll
        for (int i = 0; i < 4; ++i)
            #pragma unroll
            for (int j = 0; j < 4; ++j)
                acc[i][j] = __builtin_amdgcn_mfma_f32_16x16x32_bf16(
                    af[i], bfb[j], acc[i][j], 0, 0, 0);
        __syncthreads();
    }

    bf16_t* Ls = smem + wave * 4352;          // [64][stride 68]
    const int bq     = (m0 + wrow) >> 11;
    const int hd     = ((n0 + wcol) >> 6) & 15;
    const int t_base = (m0 + wrow) & 2047;

    if (sel < 2) {
        bf16_t* OUT = (sel == 0) ? qo : ko;
        #pragma unroll
        for (int i = 0; i < 4; ++i) {
            #pragma unroll
            for (int j = 0; j < 4; ++j) {
                #pragma unroll
                for (int r = 0; r < 4; ++r) {
                    const int mrow = i * 16 + quad * 4 + r;
                    const int dcol = j * 16 + l16;
                    float v = acc[i][j][r];
                    const float vp = __shfl_xor(v, 1);   // pair d^1 = lane^1
                    const int t  = t_base + mrow;
                    const int kk = dcol >> 1;
                    const float freq = exp2f((float)kk * -0.4152410118609203f);
                    float sn, cs;
                    fast_sincos((float)t * freq, &sn, &cs);
                    v = ((dcol & 1) == 0) ? (cs * v - sn * vp) : (sn * vp + cs * v);
                    Ls[mrow * 68 + dcol] = (bf16_t)v;
                }
            }
        }
        #pragma unroll
        for (int s = 0; s < 8; ++s) {
            const int row = s * 8 + (lane >> 3);
            const int off = (lane & 7) * 8;
            const v8bf vv = *(const v8bf*)&Ls[row * 68 + off];
            *(v8bf*)(OUT + (((size_t)(bq * 16 + hd) * 2048) + t_base + row) * 64 + off) = vv;
        }
    } else {
        #pragma unroll
        for (int i = 0; i < 4; ++i)
            #pragma unroll
            for (int j = 0; j < 4; ++j) {
                v4bf p;
                #pragma unroll
                for (int r = 0; r < 4; ++r) p[r] = (bf16_t)acc[i][j][r];
                *(v4bf*)&Ls[(j * 16 + l16) * 68 + i * 16 + quad * 4] = p;
            }
        #pragma unroll
        for (int s = 0; s < 8; ++s) {
            const int drow = s * 8 + (lane >> 3);
            const int off  = (lane & 7) * 8;
            const v8bf vv = *(const v8bf*)&Ls[drow * 68 + off];
            *(v8bf*)(vo + (((size_t)(bq * 16 + hd) * 64) + drow) * 2048 + t_base + off) = vv;
        }
    }
}

// ---------------------------------------------------------------------------
// Kernel 2: causal flash attention — S^T core, 1 barrier/tile double-buffer,
// 512-thread blocks (r13 structure) + ONES-MFMA l-sum: the row-sum of P is
// computed by 2 extra MFMAs with an all-ones A-operand (replaces 16 adds +
// 2 shfls per tile-lane; MFMA pipe has 87% headroom). l recurrence
// l = alpha*l + sum becomes a 5th O-accumulator pair.
// Grid 512, XCD-grouped (4 bh/XCD) + CU-sum-balanced (34 iters per CU).
// ---------------------------------------------------------------------------
__global__ __launch_bounds__(512, 4) void attn_mfma(
    const bf16_t* __restrict__ qg,
    const bf16_t* __restrict__ kg,
    const bf16_t* __restrict__ vtg,
    bf16_t* __restrict__ og)
{
    __shared__ __align__(16) bf16_t Ks[2][64 * 72];
    __shared__ __align__(16) bf16_t Vs[2][64 * 72];
    __shared__ __align__(16) bf16_t Ps[8][16 * 72];

    const int tid  = threadIdx.x;          // 0..511
    const int wave = tid >> 6;             // 0..7
    const int lane = tid & 63;
    const int l16  = lane & 15;
    const int quad = lane >> 4;

    const int i  = blockIdx.x;             // 0..511
    const int tt = i >> 3;                 // 0..63
    const int u  = tt & 15;
    const int g  = tt >> 4;                // 0..3
    const int q128 = (((g + 1) >> 1) & 1) ? (15 - u) : u;
    const int bh = (i & 7) * 4 + g;
    const int b = bh >> 4, hh = bh & 15;

    const bf16_t* Kb = kg  + (size_t)bh * 2048 * 64;
    const bf16_t* Vb = vtg + (size_t)bh * 64 * 2048;

    const int qglb = q128 * 128 + wave * 16 + l16;   // this lane's Q row
    const int diag_kt = 2 * q128 + (wave >> 2);      // wave's diagonal K-tile
    const int ktmax = 2 * q128 + 1;

    // Q B-frags; fold 1/8 * log2(e) (softmax runs in exp2 domain)
    const bf16_t* qrow = qg + ((size_t)bh * 2048 + qglb) * 64;
    v8bf qf[2];
    qf[0] = *(const v8bf*)(qrow + quad * 8);
    qf[1] = *(const v8bf*)(qrow + 32 + quad * 8);
    #pragma unroll
    for (int e = 0; e < 8; ++e) {
        qf[0][e] = (bf16_t)((float)qf[0][e] * 0.18033688011112042f);
        qf[1][e] = (bf16_t)((float)qf[1][e] * 0.18033688011112042f);
    }

    // all-ones A-frag for the l-sum MFMA
    v8bf ones1;
    #pragma unroll
    for (int e = 0; e < 8; ++e) ones1[e] = (bf16_t)1.0f;

    float m_r = -1e30f;
    v4f l_acc = (v4f)(0.0f);               // all 4 regs hold the same l value
    v4f o_acc[4];
    #pragma unroll
    for (int d = 0; d < 4; ++d) o_acc[d] = (v4f)(0.0f);

    // stage tile 0 into buffer 0 (512 threads x 16 B = one 8 KB tile each)
    const int srow = tid >> 3;
    const int scol = (tid & 7) * 8;
    {
        const v8bf k0 = *(const v8bf*)(Kb + (size_t)srow * 64 + scol);
        const v8bf v0 = *(const v8bf*)(Vb + (size_t)srow * 2048 + scol);
        *(v8bf*)&Ks[0][srow * 72 + scol] = k0;
        *(v8bf*)&Vs[0][srow * 72 + scol] = v0;
    }

    for (int kt = 0; kt <= ktmax; ++kt) {
        const int cur = kt & 1;
        const int nxt = cur ^ 1;
        __syncthreads();   // buf[cur] complete; prior reads of buf[nxt] done

        // issue prefetch of tile kt+1 (vmcnt wait deferred to the ds_write)
        v8bf kreg, vreg;
        if (kt < ktmax) {
            kreg = *(const v8bf*)(Kb + ((size_t)(kt + 1) * 64 + srow) * 64 + scol);
            vreg = *(const v8bf*)(Vb + (size_t)srow * 2048 + (kt + 1) * 64 + scol);
        }

        const bool active = (kt * 64) <= (q128 * 128 + wave * 16 + 15);
        if (active) {
            // ---- S^T tile ----
            v4f s_acc[4];
            #pragma unroll
            for (int kblk = 0; kblk < 4; ++kblk) s_acc[kblk] = (v4f)(0.0f);
            #pragma unroll
            for (int kblk = 0; kblk < 4; ++kblk) {
                const v8bf kf0 = *(const v8bf*)&Ks[cur][(kblk * 16 + l16) * 72 + quad * 8];
                const v8bf kf1 = *(const v8bf*)&Ks[cur][(kblk * 16 + l16) * 72 + 32 + quad * 8];
                s_acc[kblk] = __builtin_amdgcn_mfma_f32_16x16x32_bf16(
                    kf0, qf[0], s_acc[kblk], 0, 0, 0);
                s_acc[kblk] = __builtin_amdgcn_mfma_f32_16x16x32_bf16(
                    kf1, qf[1], s_acc[kblk], 0, 0, 0);
            }

            if (kt == diag_kt) {   // causal mask only on the diagonal tile
                #pragma unroll
                for (int kblk = 0; kblk < 4; ++kblk)
                    #pragma unroll
                    for (int r = 0; r < 4; ++r)
                        if (kt * 64 + kblk * 16 + quad * 4 + r > qglb)
                            s_acc[kblk][r] = -1e30f;
            }

            // ---- online softmax max (exp2 domain) ----
            float mx = -1e30f;
            #pragma unroll
            for (int kblk = 0; kblk < 4; ++kblk)
                #pragma unroll
                for (int r = 0; r < 4; ++r) mx = fmaxf(mx, s_acc[kblk][r]);
            mx = fmaxf(mx, __shfl_xor(mx, 16));
            mx = fmaxf(mx, __shfl_xor(mx, 32));
            const float m_new = fmaxf(m_r, mx);
            const float alpha = exp2f(m_r - m_new);
            m_r = m_new;
            #pragma unroll
            for (int kblk = 0; kblk < 4; ++kblk)
                #pragma unroll
                for (int r = 0; r < 4; ++r)
                    s_acc[kblk][r] = exp2f(s_acc[kblk][r] - m_new);

            // ---- P -> Ps[wave][m=l16][k]; O and l scaled by alpha ----
            #pragma unroll
            for (int kblk = 0; kblk < 4; ++kblk) {
                v4bf p;
                #pragma unroll
                for (int r = 0; r < 4; ++r) p[r] = (bf16_t)s_acc[kblk][r];
                *(v4bf*)&Ps[wave][l16 * 72 + kblk * 16 + quad * 4] = p;
            }
            #pragma unroll
            for (int d = 0; d < 4; ++d) o_acc[d] *= alpha;
            l_acc *= alpha;

            // ---- O^T += V^T P^T; l += ones * P^T (2 extra MFMAs) ----
            const v8bf pf0 = *(const v8bf*)&Ps[wave][l16 * 72 + quad * 8];
            const v8bf pf1 = *(const v8bf*)&Ps[wave][l16 * 72 + 32 + quad * 8];
            #pragma unroll
            for (int dblk = 0; dblk < 4; ++dblk) {
                const v8bf vf0 = *(const v8bf*)&Vs[cur][(dblk * 16 + l16) * 72 + quad * 8];
                const v8bf vf1 = *(const v8bf*)&Vs[cur][(dblk * 16 + l16) * 72 + 32 + quad * 8];
                o_acc[dblk] = __builtin_amdgcn_mfma_f32_16x16x32_bf16(
                    vf0, pf0, o_acc[dblk], 0, 0, 0);
                o_acc[dblk] = __builtin_amdgcn_mfma_f32_16x16x32_bf16(
                    vf1, pf1, o_acc[dblk], 0, 0, 0);
            }
            l_acc = __builtin_amdgcn_mfma_f32_16x16x32_bf16(ones1, pf0, l_acc, 0, 0, 0);
            l_acc = __builtin_amdgcn_mfma_f32_16x16x32_bf16(ones1, pf1, l_acc, 0, 0, 0);
        }

        // write next tile into the other buffer (overlaps others' compute)
        if (kt < ktmax) {
            *(v8bf*)&Ks[nxt][srow * 72 + scol] = kreg;
            *(v8bf*)&Vs[nxt][srow * 72 + scol] = vreg;
        }
    }

    // ---- epilogue: O^T col m=l16 -> og[b][t][hh*64+d], v4bf stores ----
    const float inv_l = 1.0f / l_acc[0];   // all regs equal (ones-A rows)
    const size_t base = ((size_t)b * 2048 + qglb) * 1024 + hh * 64;
    #pragma unroll
    for (int dblk = 0; dblk < 4; ++dblk) {
        v4bf o;
        #pragma unroll
        for (int r = 0; r < 4; ++r) o[r] = (bf16_t)(o_acc[dblk][r] * inv_l);
        *(v4bf*)(og + base + dblk * 16 + quad * 4) = o;
    }
}

// ---------------------------------------------------------------------------
// Kernel 3: d_out(fp32) = og @ wo^T. 128x64 tiles, 512 blocks (2/CU).
// ---------------------------------------------------------------------------
__global__ __launch_bounds__(256) void out_gemm(
    const bf16_t* __restrict__ A,   // og [4096][1024] bf16
    const bf16_t* __restrict__ W,   // wob [1024][1024] bf16
    float* __restrict__ C)
{
    __shared__ __align__(16) float smemf[4352];
    bf16_t* As = (bf16_t*)smemf;        // [128][32]
    bf16_t* Bs = As + 4096;             // [64][32]

    const int tid = threadIdx.x;
    const int n0  = blockIdx.x * 64;
    const int m0  = blockIdx.y * 128;

    const int wave = tid >> 6;
    const int lane = tid & 63;
    const int l16  = lane & 15;
    const int quad = lane >> 4;
    const int wrow = (wave >> 1) * 64;
    const int wcol = (wave & 1) * 32;

    v4f acc[4][2];
    #pragma unroll
    for (int i = 0; i < 4; ++i)
        #pragma unroll
        for (int j = 0; j < 2; ++j) acc[i][j] = (v4f)(0.0f);

    for (int kt = 0; kt < 32; ++kt) {
        const int k0 = kt * 32;
        #pragma unroll
        for (int rep = 0; rep < 2; ++rep) {
            const int c   = rep * 256 + tid;
            const int row = c >> 2;
            const int col = (c & 3) * 8;
            load_lds16(A + (size_t)(m0 + row) * 1024 + k0 + col, &As[c * 8]);
        }
        {
            const int row = tid >> 2;
            const int col = (tid & 3) * 8;
            load_lds16(W + (size_t)(n0 + row) * 1024 + k0 + col, &Bs[tid * 8]);
        }
        __syncthreads();

        v8bf af[4], bfb[2];
        #pragma unroll
        for (int i = 0; i < 4; ++i)
            af[i]  = *(const v8bf*)&As[(wrow + i * 16 + l16) * 32 + quad * 8];
        #pragma unroll
        for (int j = 0; j < 2; ++j)
            bfb[j] = *(const v8bf*)&Bs[(wcol + j * 16 + l16) * 32 + quad * 8];
        #pragma unroll
        for (int i = 0; i < 4; ++i)
            #pragma unroll
            for (int j = 0; j < 2; ++j)
                acc[i][j] = __builtin_amdgcn_mfma_f32_16x16x32_bf16(
                    af[i], bfb[j], acc[i][j], 0, 0, 0);
        __syncthreads();
    }

    float* Lw = smemf + wave * 1088;
    #pragma unroll
    for (int half = 0; half < 2; ++half) {
        #pragma unroll
        for (int ii = 0; ii < 2; ++ii) {
            const int i = half * 2 + ii;
            #pragma unroll
            for (int j = 0; j < 2; ++j)
                #pragma unroll
                for (int r = 0; r < 4; ++r)
                    Lw[(ii * 16 + quad * 4 + r) * 34 + j * 16 + l16] = acc[i][j][r];
        }
        // same-wave LDS RAW: DS pipe in-order per wave
        #pragma unroll
        for (int s = 0; s < 8; ++s) {
            const int row = s * 4 + (lane >> 4);      // 0..31
            const float2 vv = *(const float2*)&Lw[row * 34 + l16 * 2];
            *(float2*)(C + (size_t)(m0 + wrow + half * 32 + row) * 1024
                         + n0 + wcol + l16 * 2) = vv;
        }
    }
}

// ---------------------------------------------------------------------------
extern "C" void kernel_launch(void* const* d_in, const int* in_sizes, int n_in,
                              void* d_out, int out_size, void* d_ws, size_t ws_size,
                              hipStream_t stream) {
    const float* h  = (const float*)d_in[0];
    const float* wq = (const float*)d_in[1];
    const float* wk = (const float*)d_in[2];
    const float* wv = (const float*)d_in[3];
    const float* wo = (const float*)d_in[4];

    const size_t NH = (size_t)4096 * 1024;   // 4M
    const size_t NW = (size_t)1024 * 1024;   // 1M

    bf16_t* wob = (bf16_t*)d_ws;
    bf16_t* qw  = wob + NW;                  // [32][2048][64]
    bf16_t* kw  = qw + NH;
    bf16_t* vw  = kw + NH;                   // [32][64][2048] (V^T)
    bf16_t* og  = vw + NH;                   // [4096][1024]
    // total: 17M elems = 34 MB

    cvt_wo<<<dim3(512), dim3(256), 0, stream>>>(wo, wob);
    qkv_gemm_rope<<<dim3(24, 32), dim3(256), 0, stream>>>(
        h, wq, wk, wv, qw, kw, vw);
    attn_mfma<<<dim3(512), dim3(512), 0, stream>>>(qw, kw, vw, og);
    out_gemm<<<dim3(16, 32), dim3(256), 0, stream>>>(og, wob, (float*)d_out);
}

// Round 15
// 184.906 us; speedup vs baseline: 1.0500x; 1.0500x over previous
//
#include <hip/hip_runtime.h>
#include <math.h>

typedef __bf16 bf16_t;
typedef __bf16 v8bf __attribute__((ext_vector_type(8)));
typedef __bf16 v4bf __attribute__((ext_vector_type(4)));
typedef float  v4f  __attribute__((ext_vector_type(4)));

#define AS1 __attribute__((address_space(1)))
#define AS3 __attribute__((address_space(3)))

// async global->LDS 16B copy; LDS dest = wave-uniform base + lane*16
static __device__ __forceinline__ void load_lds16(const bf16_t* g, bf16_t* l) {
    __builtin_amdgcn_global_load_lds((AS1 void*)const_cast<bf16_t*>(g),
                                     (AS3 void*)l, 16, 0, 0);
}

// sin/cos via native HW ops with explicit revolution reduction (no libcall)
static __device__ __forceinline__ void fast_sincos(float ang, float* sn, float* cs) {
    float rv = ang * 0.15915494309189535f;
    rv -= floorf(rv);
    const float a = rv * 6.283185307179586f;
    *sn = __sinf(a);
    *cs = __cosf(a);
}

// ---------------------------------------------------------------------------
// Kernel 0: fp32 -> bf16 for h + 4 weights. 8M elems, 8/thread.
// (rule from r6/r14: convert once in a streaming pass; keep hot GEMM loops
// bf16 — fusing fp32 reads into the GEMM K-loop doubles FETCH and loses)
// ---------------------------------------------------------------------------
__global__ __launch_bounds__(256) void cvt_fp32_bf16(
    const float* __restrict__ h,  const float* __restrict__ wq,
    const float* __restrict__ wk, const float* __restrict__ wv,
    const float* __restrict__ wo,
    bf16_t* __restrict__ hb,  bf16_t* __restrict__ wqb,
    bf16_t* __restrict__ wkb, bf16_t* __restrict__ wvb,
    bf16_t* __restrict__ wob)
{
    const size_t HM = (size_t)4 << 20;
    const size_t i8 = ((size_t)blockIdx.x * 256 + threadIdx.x) * 8;
    const float* src; bf16_t* dst; size_t off;
    if (i8 < HM) { src = h; dst = hb; off = i8; }
    else {
        const size_t r = (i8 - HM) >> 20;
        off = (i8 - HM) & (((size_t)1 << 20) - 1);
        src = (r == 0) ? wq  : (r == 1) ? wk  : (r == 2) ? wv  : wo;
        dst = (r == 0) ? wqb : (r == 1) ? wkb : (r == 2) ? wvb : wob;
    }
    const float4 a = *(const float4*)(src + off);
    const float4 b = *(const float4*)(src + off + 4);
    v8bf o;
    o[0]=(bf16_t)a.x; o[1]=(bf16_t)a.y; o[2]=(bf16_t)a.z; o[3]=(bf16_t)a.w;
    o[4]=(bf16_t)b.x; o[5]=(bf16_t)b.y; o[6]=(bf16_t)b.z; o[7]=(bf16_t)b.w;
    *(v8bf*)(dst + off) = o;
}

// ---------------------------------------------------------------------------
// Kernel 1: QKV = h @ [wq|wk|wv]^T, fused RoPE on Q,K (inline transcendentals).
// All-bf16 inputs, global_load_lds staging. Q,K: [32][2048][64];
// V TRANSPOSED: [32][64][2048]. Epilogue stores wave-coalesced v8bf via LDS.
// ---------------------------------------------------------------------------
__global__ __launch_bounds__(256) void qkv_gemm_rope(
    const bf16_t* __restrict__ A,   // h bf16 [4096][1024]
    const bf16_t* __restrict__ wq,
    const bf16_t* __restrict__ wk,
    const bf16_t* __restrict__ wv,
    bf16_t* __restrict__ qo, bf16_t* __restrict__ ko, bf16_t* __restrict__ vo)
{
    __shared__ __align__(16) bf16_t smem[17408];
    bf16_t* As = smem;
    bf16_t* Bs = smem + 4096;

    const int tid = threadIdx.x;
    const int n0  = blockIdx.x * 128;
    const int m0  = blockIdx.y * 128;
    const int sel = n0 >> 10;               // 0=Q 1=K 2=V
    const bf16_t* W = (sel == 0) ? wq : (sel == 1) ? wk : wv;
    const int wr0 = n0 & 1023;

    const int wave = tid >> 6;
    const int lane = tid & 63;
    const int l16  = lane & 15;
    const int quad = lane >> 4;
    const int wrow = (wave >> 1) * 64;
    const int wcol = (wave & 1) * 64;

    v4f acc[4][4];
    #pragma unroll
    for (int i = 0; i < 4; ++i)
        #pragma unroll
        for (int j = 0; j < 4; ++j) acc[i][j] = (v4f)(0.0f);

    for (int kt = 0; kt < 32; ++kt) {
        const int k0 = kt * 32;
        #pragma unroll
        for (int rep = 0; rep < 2; ++rep) {
            const int c   = rep * 256 + tid;
            const int row = c >> 2;
            const int col = (c & 3) * 8;
            load_lds16(A + (size_t)(m0 + row) * 1024 + k0 + col, &As[c * 8]);
            load_lds16(W + (size_t)(wr0 + row) * 1024 + k0 + col, &Bs[c * 8]);
        }
        __syncthreads();

        v8bf af[4], bfb[4];
        #pragma unroll
        for (int i = 0; i < 4; ++i) {
            af[i]  = *(const v8bf*)&As[(wrow + i * 16 + l16) * 32 + quad * 8];
            bfb[i] = *(const v8bf*)&Bs[(wcol + i * 16 + l16) * 32 + quad * 8];
        }
        #pragma unroll
        for (int i = 0; i < 4; ++i)
            #pragma unroll
            for (int j = 0; j < 4; ++j)
                acc[i][j] = __builtin_amdgcn_mfma_f32_16x16x32_bf16(
                    af[i], bfb[j], acc[i][j], 0, 0, 0);
        __syncthreads();
    }

    bf16_t* Ls = smem + wave * 4352;          // [64][stride 68]
    const int bq     = (m0 + wrow) >> 11;
    const int hd     = ((n0 + wcol) >> 6) & 15;
    const int t_base = (m0 + wrow) & 2047;

    if (sel < 2) {
        bf16_t* OUT = (sel == 0) ? qo : ko;
        #pragma unroll
        for (int i = 0; i < 4; ++i) {
            #pragma unroll
            for (int j = 0; j < 4; ++j) {
                #pragma unroll
                for (int r = 0; r < 4; ++r) {
                    const int mrow = i * 16 + quad * 4 + r;
                    const int dcol = j * 16 + l16;
                    float v = acc[i][j][r];
                    const float vp = __shfl_xor(v, 1);   // pair d^1 = lane^1
                    const int t  = t_base + mrow;
                    const int kk = dcol >> 1;
                    const float freq = exp2f((float)kk * -0.4152410118609203f);
                    float sn, cs;
                    fast_sincos((float)t * freq, &sn, &cs);
                    v = ((dcol & 1) == 0) ? (cs * v - sn * vp) : (sn * vp + cs * v);
                    Ls[mrow * 68 + dcol] = (bf16_t)v;
                }
            }
        }
        #pragma unroll
        for (int s = 0; s < 8; ++s) {
            const int row = s * 8 + (lane >> 3);
            const int off = (lane & 7) * 8;
            const v8bf vv = *(const v8bf*)&Ls[row * 68 + off];
            *(v8bf*)(OUT + (((size_t)(bq * 16 + hd) * 2048) + t_base + row) * 64 + off) = vv;
        }
    } else {
        #pragma unroll
        for (int i = 0; i < 4; ++i)
            #pragma unroll
            for (int j = 0; j < 4; ++j) {
                v4bf p;
                #pragma unroll
                for (int r = 0; r < 4; ++r) p[r] = (bf16_t)acc[i][j][r];
                *(v4bf*)&Ls[(j * 16 + l16) * 68 + i * 16 + quad * 4] = p;
            }
        #pragma unroll
        for (int s = 0; s < 8; ++s) {
            const int drow = s * 8 + (lane >> 3);
            const int off  = (lane & 7) * 8;
            const v8bf vv = *(const v8bf*)&Ls[drow * 68 + off];
            *(v8bf*)(vo + (((size_t)(bq * 16 + hd) * 64) + drow) * 2048 + t_base + off) = vv;
        }
    }
}

// ---------------------------------------------------------------------------
// Kernel 2: causal flash attention — S^T core, 1 barrier/tile double-buffer,
// 512-thread blocks + ONES-MFMA l-sum (row-sum of P via 2 extra MFMAs with
// an all-ones A-operand; l = alpha*l + sum rides a 5th accumulator).
// Grid 512, XCD-grouped (4 bh/XCD) + CU-sum-balanced (34 iters per CU).
// ---------------------------------------------------------------------------
__global__ __launch_bounds__(512, 4) void attn_mfma(
    const bf16_t* __restrict__ qg,
    const bf16_t* __restrict__ kg,
    const bf16_t* __restrict__ vtg,
    bf16_t* __restrict__ og)
{
    __shared__ __align__(16) bf16_t Ks[2][64 * 72];
    __shared__ __align__(16) bf16_t Vs[2][64 * 72];
    __shared__ __align__(16) bf16_t Ps[8][16 * 72];

    const int tid  = threadIdx.x;          // 0..511
    const int wave = tid >> 6;             // 0..7
    const int lane = tid & 63;
    const int l16  = lane & 15;
    const int quad = lane >> 4;

    const int i  = blockIdx.x;             // 0..511
    const int tt = i >> 3;                 // 0..63
    const int u  = tt & 15;
    const int g  = tt >> 4;                // 0..3
    const int q128 = (((g + 1) >> 1) & 1) ? (15 - u) : u;
    const int bh = (i & 7) * 4 + g;
    const int b = bh >> 4, hh = bh & 15;

    const bf16_t* Kb = kg  + (size_t)bh * 2048 * 64;
    const bf16_t* Vb = vtg + (size_t)bh * 64 * 2048;

    const int qglb = q128 * 128 + wave * 16 + l16;   // this lane's Q row
    const int diag_kt = 2 * q128 + (wave >> 2);      // wave's diagonal K-tile
    const int ktmax = 2 * q128 + 1;

    // Q B-frags; fold 1/8 * log2(e) (softmax runs in exp2 domain)
    const bf16_t* qrow = qg + ((size_t)bh * 2048 + qglb) * 64;
    v8bf qf[2];
    qf[0] = *(const v8bf*)(qrow + quad * 8);
    qf[1] = *(const v8bf*)(qrow + 32 + quad * 8);
    #pragma unroll
    for (int e = 0; e < 8; ++e) {
        qf[0][e] = (bf16_t)((float)qf[0][e] * 0.18033688011112042f);
        qf[1][e] = (bf16_t)((float)qf[1][e] * 0.18033688011112042f);
    }

    // all-ones A-frag for the l-sum MFMA
    v8bf ones1;
    #pragma unroll
    for (int e = 0; e < 8; ++e) ones1[e] = (bf16_t)1.0f;

    float m_r = -1e30f;
    v4f l_acc = (v4f)(0.0f);               // all 4 regs hold the same l value
    v4f o_acc[4];
    #pragma unroll
    for (int d = 0; d < 4; ++d) o_acc[d] = (v4f)(0.0f);

    // stage tile 0 into buffer 0 (512 threads x 16 B = one 8 KB tile each)
    const int srow = tid >> 3;
    const int scol = (tid & 7) * 8;
    {
        const v8bf k0 = *(const v8bf*)(Kb + (size_t)srow * 64 + scol);
        const v8bf v0 = *(const v8bf*)(Vb + (size_t)srow * 2048 + scol);
        *(v8bf*)&Ks[0][srow * 72 + scol] = k0;
        *(v8bf*)&Vs[0][srow * 72 + scol] = v0;
    }

    for (int kt = 0; kt <= ktmax; ++kt) {
        const int cur = kt & 1;
        const int nxt = cur ^ 1;
        __syncthreads();   // buf[cur] complete; prior reads of buf[nxt] done

        // issue prefetch of tile kt+1 (vmcnt wait deferred to the ds_write)
        v8bf kreg, vreg;
        if (kt < ktmax) {
            kreg = *(const v8bf*)(Kb + ((size_t)(kt + 1) * 64 + srow) * 64 + scol);
            vreg = *(const v8bf*)(Vb + (size_t)srow * 2048 + (kt + 1) * 64 + scol);
        }

        const bool active = (kt * 64) <= (q128 * 128 + wave * 16 + 15);
        if (active) {
            // ---- S^T tile ----
            v4f s_acc[4];
            #pragma unroll
            for (int kblk = 0; kblk < 4; ++kblk) s_acc[kblk] = (v4f)(0.0f);
            #pragma unroll
            for (int kblk = 0; kblk < 4; ++kblk) {
                const v8bf kf0 = *(const v8bf*)&Ks[cur][(kblk * 16 + l16) * 72 + quad * 8];
                const v8bf kf1 = *(const v8bf*)&Ks[cur][(kblk * 16 + l16) * 72 + 32 + quad * 8];
                s_acc[kblk] = __builtin_amdgcn_mfma_f32_16x16x32_bf16(
                    kf0, qf[0], s_acc[kblk], 0, 0, 0);
                s_acc[kblk] = __builtin_amdgcn_mfma_f32_16x16x32_bf16(
                    kf1, qf[1], s_acc[kblk], 0, 0, 0);
            }

            if (kt == diag_kt) {   // causal mask only on the diagonal tile
                #pragma unroll
                for (int kblk = 0; kblk < 4; ++kblk)
                    #pragma unroll
                    for (int r = 0; r < 4; ++r)
                        if (kt * 64 + kblk * 16 + quad * 4 + r > qglb)
                            s_acc[kblk][r] = -1e30f;
            }

            // ---- online softmax max (exp2 domain) ----
            float mx = -1e30f;
            #pragma unroll
            for (int kblk = 0; kblk < 4; ++kblk)
                #pragma unroll
                for (int r = 0; r < 4; ++r) mx = fmaxf(mx, s_acc[kblk][r]);
            mx = fmaxf(mx, __shfl_xor(mx, 16));
            mx = fmaxf(mx, __shfl_xor(mx, 32));
            const float m_new = fmaxf(m_r, mx);
            const float alpha = exp2f(m_r - m_new);
            m_r = m_new;
            #pragma unroll
            for (int kblk = 0; kblk < 4; ++kblk)
                #pragma unroll
                for (int r = 0; r < 4; ++r)
                    s_acc[kblk][r] = exp2f(s_acc[kblk][r] - m_new);

            // ---- P -> Ps[wave][m=l16][k]; O and l scaled by alpha ----
            #pragma unroll
            for (int kblk = 0; kblk < 4; ++kblk) {
                v4bf p;
                #pragma unroll
                for (int r = 0; r < 4; ++r) p[r] = (bf16_t)s_acc[kblk][r];
                *(v4bf*)&Ps[wave][l16 * 72 + kblk * 16 + quad * 4] = p;
            }
            #pragma unroll
            for (int d = 0; d < 4; ++d) o_acc[d] *= alpha;
            l_acc *= alpha;

            // ---- O^T += V^T P^T; l += ones * P^T (2 extra MFMAs) ----
            const v8bf pf0 = *(const v8bf*)&Ps[wave][l16 * 72 + quad * 8];
            const v8bf pf1 = *(const v8bf*)&Ps[wave][l16 * 72 + 32 + quad * 8];
            #pragma unroll
            for (int dblk = 0; dblk < 4; ++dblk) {
                const v8bf vf0 = *(const v8bf*)&Vs[cur][(dblk * 16 + l16) * 72 + quad * 8];
                const v8bf vf1 = *(const v8bf*)&Vs[cur][(dblk * 16 + l16) * 72 + 32 + quad * 8];
                o_acc[dblk] = __builtin_amdgcn_mfma_f32_16x16x32_bf16(
                    vf0, pf0, o_acc[dblk], 0, 0, 0);
                o_acc[dblk] = __builtin_amdgcn_mfma_f32_16x16x32_bf16(
                    vf1, pf1, o_acc[dblk], 0, 0, 0);
            }
            l_acc = __builtin_amdgcn_mfma_f32_16x16x32_bf16(ones1, pf0, l_acc, 0, 0, 0);
            l_acc = __builtin_amdgcn_mfma_f32_16x16x32_bf16(ones1, pf1, l_acc, 0, 0, 0);
        }

        // write next tile into the other buffer (overlaps others' compute)
        if (kt < ktmax) {
            *(v8bf*)&Ks[nxt][srow * 72 + scol] = kreg;
            *(v8bf*)&Vs[nxt][srow * 72 + scol] = vreg;
        }
    }

    // ---- epilogue: O^T col m=l16 -> og[b][t][hh*64+d], v4bf stores ----
    const float inv_l = 1.0f / l_acc[0];   // all regs equal (ones-A rows)
    const size_t base = ((size_t)b * 2048 + qglb) * 1024 + hh * 64;
    #pragma unroll
    for (int dblk = 0; dblk < 4; ++dblk) {
        v4bf o;
        #pragma unroll
        for (int r = 0; r < 4; ++r) o[r] = (bf16_t)(o_acc[dblk][r] * inv_l);
        *(v4bf*)(og + base + dblk * 16 + quad * 4) = o;
    }
}

// ---------------------------------------------------------------------------
// Kernel 3: d_out(fp32) = og @ wo^T. 128x64 tiles, 512 blocks (2/CU).
// ---------------------------------------------------------------------------
__global__ __launch_bounds__(256) void out_gemm(
    const bf16_t* __restrict__ A,   // og [4096][1024] bf16
    const bf16_t* __restrict__ W,   // wob [1024][1024] bf16
    float* __restrict__ C)
{
    __shared__ __align__(16) float smemf[4352];
    bf16_t* As = (bf16_t*)smemf;        // [128][32]
    bf16_t* Bs = As + 4096;             // [64][32]

    const int tid = threadIdx.x;
    const int n0  = blockIdx.x * 64;
    const int m0  = blockIdx.y * 128;

    const int wave = tid >> 6;
    const int lane = tid & 63;
    const int l16  = lane & 15;
    const int quad = lane >> 4;
    const int wrow = (wave >> 1) * 64;
    const int wcol = (wave & 1) * 32;

    v4f acc[4][2];
    #pragma unroll
    for (int i = 0; i < 4; ++i)
        #pragma unroll
        for (int j = 0; j < 2; ++j) acc[i][j] = (v4f)(0.0f);

    for (int kt = 0; kt < 32; ++kt) {
        const int k0 = kt * 32;
        #pragma unroll
        for (int rep = 0; rep < 2; ++rep) {
            const int c   = rep * 256 + tid;
            const int row = c >> 2;
            const int col = (c & 3) * 8;
            load_lds16(A + (size_t)(m0 + row) * 1024 + k0 + col, &As[c * 8]);
        }
        {
            const int row = tid >> 2;
            const int col = (tid & 3) * 8;
            load_lds16(W + (size_t)(n0 + row) * 1024 + k0 + col, &Bs[tid * 8]);
        }
        __syncthreads();

        v8bf af[4], bfb[2];
        #pragma unroll
        for (int i = 0; i < 4; ++i)
            af[i]  = *(const v8bf*)&As[(wrow + i * 16 + l16) * 32 + quad * 8];
        #pragma unroll
        for (int j = 0; j < 2; ++j)
            bfb[j] = *(const v8bf*)&Bs[(wcol + j * 16 + l16) * 32 + quad * 8];
        #pragma unroll
        for (int i = 0; i < 4; ++i)
            #pragma unroll
            for (int j = 0; j < 2; ++j)
                acc[i][j] = __builtin_amdgcn_mfma_f32_16x16x32_bf16(
                    af[i], bfb[j], acc[i][j], 0, 0, 0);
        __syncthreads();
    }

    float* Lw = smemf + wave * 1088;
    #pragma unroll
    for (int half = 0; half < 2; ++half) {
        #pragma unroll
        for (int ii = 0; ii < 2; ++ii) {
            const int i = half * 2 + ii;
            #pragma unroll
            for (int j = 0; j < 2; ++j)
                #pragma unroll
                for (int r = 0; r < 4; ++r)
                    Lw[(ii * 16 + quad * 4 + r) * 34 + j * 16 + l16] = acc[i][j][r];
        }
        // same-wave LDS RAW: DS pipe in-order per wave
        #pragma unroll
        for (int s = 0; s < 8; ++s) {
            const int row = s * 4 + (lane >> 4);      // 0..31
            const float2 vv = *(const float2*)&Lw[row * 34 + l16 * 2];
            *(float2*)(C + (size_t)(m0 + wrow + half * 32 + row) * 1024
                         + n0 + wcol + l16 * 2) = vv;
        }
    }
}

// ---------------------------------------------------------------------------
extern "C" void kernel_launch(void* const* d_in, const int* in_sizes, int n_in,
                              void* d_out, int out_size, void* d_ws, size_t ws_size,
                              hipStream_t stream) {
    const float* h  = (const float*)d_in[0];
    const float* wq = (const float*)d_in[1];
    const float* wk = (const float*)d_in[2];
    const float* wv = (const float*)d_in[3];
    const float* wo = (const float*)d_in[4];

    const size_t NH = (size_t)4096 * 1024;   // 4M
    const size_t NW = (size_t)1024 * 1024;   // 1M

    bf16_t* hb  = (bf16_t*)d_ws;
    bf16_t* wqb = hb  + NH;
    bf16_t* wkb = wqb + NW;
    bf16_t* wvb = wkb + NW;
    bf16_t* wob = wvb + NW;
    bf16_t* qw  = wob + NW;                  // [32][2048][64]
    bf16_t* kw  = qw + NH;
    bf16_t* vw  = kw + NH;                   // [32][64][2048] (V^T)
    bf16_t* og  = hb;                        // alias: hb dead after qkv
    // total: 20M elems = 40 MB

    cvt_fp32_bf16<<<dim3(4096), dim3(256), 0, stream>>>(
        h, wq, wk, wv, wo, hb, wqb, wkb, wvb, wob);
    qkv_gemm_rope<<<dim3(24, 32), dim3(256), 0, stream>>>(
        hb, wqb, wkb, wvb, qw, kw, vw);
    attn_mfma<<<dim3(512), dim3(512), 0, stream>>>(qw, kw, vw, og);
    out_gemm<<<dim3(16, 32), dim3(256), 0, stream>>>(og, wob, (float*)d_out);
}